// Round 17
// baseline (318.027 us; speedup 1.0000x reference)
//
#include <hip/hip_runtime.h>
#include <hip/hip_bf16.h>
#include <math.h>

typedef __bf16 bf16;
typedef __bf16 bf16x2 __attribute__((ext_vector_type(2)));
typedef __bf16 bf16x4 __attribute__((ext_vector_type(4)));
typedef __bf16 bf16x8 __attribute__((ext_vector_type(8)));
typedef float  f32x2  __attribute__((ext_vector_type(2)));
typedef float  f32x4  __attribute__((ext_vector_type(4)));

#define SEQ 4096
#define DM  384
#define NH  6
#define DK  64
#define NB  2
#define WN  (DM * DM)
#define EPSLN 1e-6f

// dual-dtype scalar load: f32 ? float : bf16   (flag is a VALUE, wave-uniform)
__device__ __forceinline__ float ldT(const void* p, size_t i, int f32) {
    return f32 ? ((const float*)p)[i] : (float)(((const bf16*)p)[i]);
}

// ---------------------------------------------------------------------------
// z = LN(LN(x, ra, rb), a0, b0)  — torch style: unbiased std, /(std+eps)
// Paired (x2) vector loads for x and params.
// ---------------------------------------------------------------------------
__global__ __launch_bounds__(256) void ln2_kernel(
    const void* __restrict__ x, int xf32,
    const float* __restrict__ ra, const float* __restrict__ rb,
    const float* __restrict__ a0, const float* __restrict__ b0, bf16* __restrict__ z)
{
    int row  = blockIdx.x * 4 + (threadIdx.x >> 6);
    int lane = threadIdx.x & 63;
    size_t base = (size_t)row * DM;

    float v[6];
    float s = 0.f;
    #pragma unroll
    for (int i = 0; i < 3; i++) {
        int c = lane * 2 + i * 128;
        float t0, t1;
        if (xf32) {
            f32x2 t = *(const f32x2*)((const float*)x + base + c);
            t0 = t[0]; t1 = t[1];
        } else {
            bf16x2 u = *(const bf16x2*)((const bf16*)x + base + c);
            t0 = (float)u[0]; t1 = (float)u[1];
        }
        v[2 * i] = t0; v[2 * i + 1] = t1; s += t0 + t1;
    }
    #pragma unroll
    for (int off = 1; off < 64; off <<= 1) s += __shfl_xor(s, off);
    float m = s * (1.f / DM);
    float sq = 0.f;
    #pragma unroll
    for (int i = 0; i < 6; i++) { float d = v[i] - m; sq += d * d; }
    #pragma unroll
    for (int off = 1; off < 64; off <<= 1) sq += __shfl_xor(sq, off);
    float inv = 1.f / (sqrtf(sq * (1.f / (DM - 1))) + EPSLN);

    s = 0.f;
    #pragma unroll
    for (int i = 0; i < 3; i++) {
        int c = lane * 2 + i * 128;
        f32x2 rav = *(const f32x2*)(ra + c);
        f32x2 rbv = *(const f32x2*)(rb + c);
        v[2 * i]     = rav[0] * (v[2 * i] - m) * inv + rbv[0];
        v[2 * i + 1] = rav[1] * (v[2 * i + 1] - m) * inv + rbv[1];
        s += v[2 * i] + v[2 * i + 1];
    }
    #pragma unroll
    for (int off = 1; off < 64; off <<= 1) s += __shfl_xor(s, off);
    m = s * (1.f / DM);
    sq = 0.f;
    #pragma unroll
    for (int i = 0; i < 6; i++) { float d = v[i] - m; sq += d * d; }
    #pragma unroll
    for (int off = 1; off < 64; off <<= 1) sq += __shfl_xor(sq, off);
    inv = 1.f / (sqrtf(sq * (1.f / (DM - 1))) + EPSLN);

    bf16* zr = z + base;
    #pragma unroll
    for (int i = 0; i < 3; i++) {
        int c = lane * 2 + i * 128;
        f32x2 a0v = *(const f32x2*)(a0 + c);
        f32x2 b0v = *(const f32x2*)(b0 + c);
        bf16x2 o;
        o[0] = (bf16)(a0v[0] * (v[2 * i] - m) * inv + b0v[0]);
        o[1] = (bf16)(a0v[1] * (v[2 * i + 1] - m) * inv + b0v[1]);
        *(bf16x2*)(zr + c) = o;
    }
}

// ---------------------------------------------------------------------------
// qkv GEMM, LDS-staged, BM=128 BN=128 BK=64: wave quadrant 64x64 = 4x4 accs,
// 2.0 MFMA per LDS read (was 1.33); A re-staged 9x not 18x. grid (64,3,3).
// Weights f32, converted during staging. z=0->q, z=1->k, z=2->V^T [b][h][d][s].
// Prefetch AFTER barrier B (R11/R14 pattern).
// ---------------------------------------------------------------------------
__global__ __launch_bounds__(256) void qkv_kernel(
    const bf16* __restrict__ A,
    const float* __restrict__ wq, const float* __restrict__ wk, const float* __restrict__ wv,
    const float* __restrict__ bq, const float* __restrict__ bk, const float* __restrict__ bv,
    bf16* __restrict__ qkout, bf16* __restrict__ vt)
{
    const int z = blockIdx.z;
    const float* W    = (z == 0) ? wq : (z == 1) ? wk : wv;
    const float* bias = (z == 0) ? bq : (z == 1) ? bk : bv;

    const int t = threadIdx.x;
    const int wave = t >> 6, lane = t & 63;
    const int l15 = lane & 15, quad = lane >> 4;
    const int wr = wave >> 1, wc = wave & 1;
    const int m0 = blockIdx.x * 128;
    const int n0 = blockIdx.y * 128;

    __shared__ __attribute__((aligned(16))) bf16 As[128][72];
    __shared__ __attribute__((aligned(16))) bf16 Bs[128][72];

    const int r0 = t >> 2;            // 0..63
    const int c0 = (t & 3) * 16;      // 0,16,32,48

    const bf16*  aptr0 = A + (size_t)(m0 + r0) * DM + c0;
    const bf16*  aptr1 = A + (size_t)(m0 + 64 + r0) * DM + c0;
    const float* bptr0 = W + (size_t)(n0 + r0) * DM + c0;
    const float* bptr1 = W + (size_t)(n0 + 64 + r0) * DM + c0;

    bf16x8 ra00 = *(const bf16x8*)(aptr0);
    bf16x8 ra01 = *(const bf16x8*)(aptr0 + 8);
    bf16x8 ra10 = *(const bf16x8*)(aptr1);
    bf16x8 ra11 = *(const bf16x8*)(aptr1 + 8);
    f32x4 wv0 = *(const f32x4*)(bptr0);
    f32x4 wv1 = *(const f32x4*)(bptr0 + 4);
    f32x4 wv2 = *(const f32x4*)(bptr0 + 8);
    f32x4 wv3 = *(const f32x4*)(bptr0 + 12);
    f32x4 wv4 = *(const f32x4*)(bptr1);
    f32x4 wv5 = *(const f32x4*)(bptr1 + 4);
    f32x4 wv6 = *(const f32x4*)(bptr1 + 8);
    f32x4 wv7 = *(const f32x4*)(bptr1 + 12);

    f32x4 acc[4][4];
    #pragma unroll
    for (int mi = 0; mi < 4; mi++)
        #pragma unroll
        for (int ni = 0; ni < 4; ni++) acc[mi][ni] = (f32x4){0.f, 0.f, 0.f, 0.f};

    for (int kk = 0; kk < DM; kk += 64) {
        __syncthreads();   // barrier A (drains prev prefetch — hidden)
        *(bf16x8*)&As[r0][c0]          = ra00;
        *(bf16x8*)&As[r0][c0 + 8]      = ra01;
        *(bf16x8*)&As[64 + r0][c0]     = ra10;
        *(bf16x8*)&As[64 + r0][c0 + 8] = ra11;
        {
            bf16x8 b0v, b1v, b2v, b3v;
            #pragma unroll
            for (int j = 0; j < 4; j++) {
                b0v[j] = (bf16)wv0[j]; b0v[4 + j] = (bf16)wv1[j];
                b1v[j] = (bf16)wv2[j]; b1v[4 + j] = (bf16)wv3[j];
                b2v[j] = (bf16)wv4[j]; b2v[4 + j] = (bf16)wv5[j];
                b3v[j] = (bf16)wv6[j]; b3v[4 + j] = (bf16)wv7[j];
            }
            *(bf16x8*)&Bs[r0][c0]          = b0v;
            *(bf16x8*)&Bs[r0][c0 + 8]      = b1v;
            *(bf16x8*)&Bs[64 + r0][c0]     = b2v;
            *(bf16x8*)&Bs[64 + r0][c0 + 8] = b3v;
        }
        __syncthreads();   // barrier B
        if (kk + 64 < DM) {   // prefetch next K-tile, drains at next barrier A
            ra00 = *(const bf16x8*)(aptr0 + kk + 64);
            ra01 = *(const bf16x8*)(aptr0 + kk + 64 + 8);
            ra10 = *(const bf16x8*)(aptr1 + kk + 64);
            ra11 = *(const bf16x8*)(aptr1 + kk + 64 + 8);
            wv0 = *(const f32x4*)(bptr0 + kk + 64);
            wv1 = *(const f32x4*)(bptr0 + kk + 64 + 4);
            wv2 = *(const f32x4*)(bptr0 + kk + 64 + 8);
            wv3 = *(const f32x4*)(bptr0 + kk + 64 + 12);
            wv4 = *(const f32x4*)(bptr1 + kk + 64);
            wv5 = *(const f32x4*)(bptr1 + kk + 64 + 4);
            wv6 = *(const f32x4*)(bptr1 + kk + 64 + 8);
            wv7 = *(const f32x4*)(bptr1 + kk + 64 + 12);
        }

        #pragma unroll
        for (int kc = 0; kc < 64; kc += 32) {
            bf16x8 af[4], bf[4];
            #pragma unroll
            for (int mi = 0; mi < 4; mi++)
                af[mi] = *(const bf16x8*)&As[wr * 64 + mi * 16 + l15][kc + quad * 8];
            #pragma unroll
            for (int ni = 0; ni < 4; ni++)
                bf[ni] = *(const bf16x8*)&Bs[wc * 64 + ni * 16 + l15][kc + quad * 8];
            #pragma unroll
            for (int mi = 0; mi < 4; mi++)
                #pragma unroll
                for (int ni = 0; ni < 4; ni++)
                    acc[mi][ni] = __builtin_amdgcn_mfma_f32_16x16x32_bf16(af[mi], bf[ni], acc[mi][ni], 0, 0, 0);
        }
    }

    if (z < 2) {
        bf16* out = qkout + (size_t)z * ((size_t)NB * SEQ * DM);
        #pragma unroll
        for (int ni = 0; ni < 4; ni++) {
            int col = n0 + wc * 64 + ni * 16 + l15;
            float bb = bias[col];
            #pragma unroll
            for (int mi = 0; mi < 4; mi++) {
                #pragma unroll
                for (int r = 0; r < 4; r++) {
                    int row = m0 + wr * 64 + mi * 16 + quad * 4 + r;
                    out[(size_t)row * DM + col] = (bf16)(acc[mi][ni][r] + bb);
                }
            }
        }
    } else {
        #pragma unroll
        for (int ni = 0; ni < 4; ni++) {
            int col = n0 + wc * 64 + ni * 16 + l15;
            int h = col >> 6, d = col & 63;
            float bb = bias[col];
            #pragma unroll
            for (int mi = 0; mi < 4; mi++) {
                int row0 = m0 + wr * 64 + mi * 16 + quad * 4;
                int b = row0 >> 12, s0 = row0 & (SEQ - 1);
                bf16x4 ov;
                #pragma unroll
                for (int r = 0; r < 4; r++) ov[r] = (bf16)(acc[mi][ni][r] + bb);
                *(bf16x4*)(vt + (((size_t)b * NH + h) * DK + d) * SEQ + s0) = ov;
            }
        }
    }
}

// ---------------------------------------------------------------------------
// proj GEMM, BK=64, fused split reduce (round-15 proven, byte-identical).
// ---------------------------------------------------------------------------
__device__ __forceinline__ bf16x8 combineA(
    const bf16* __restrict__ o0, const bf16* __restrict__ o1,
    const float* __restrict__ lsum, int row, int kcol)
{
    int b = row >> 12, s = row & (SEQ - 1);
    int h = kcol >> 6;
    size_t lidx = ((size_t)b * NH + h) * SEQ + s;
    float inv = 1.f / (lsum[lidx] + lsum[(size_t)(NB * NH * SEQ) + lidx]);
    size_t idx = (size_t)row * DM + kcol;
    bf16x8 a = *(const bf16x8*)(o0 + idx);
    bf16x8 c = *(const bf16x8*)(o1 + idx);
    bf16x8 r;
    #pragma unroll
    for (int j = 0; j < 8; j++) r[j] = (bf16)(((float)a[j] + (float)c[j]) * inv);
    return r;
}

__global__ __launch_bounds__(256) void proj_kernel(
    const bf16* __restrict__ o0, const bf16* __restrict__ o1,
    const float* __restrict__ lsum,
    const float* __restrict__ wo, const float* __restrict__ bo,
    const void* __restrict__ xin, int f32in,
    void* __restrict__ xout, int f32out)
{
    const int t = threadIdx.x;
    const int wave = t >> 6, lane = t & 63;
    const int l15 = lane & 15, quad = lane >> 4;
    const int wr = wave >> 1, wc = wave & 1;
    const int m0 = blockIdx.x * 64;
    const int n0 = blockIdx.y * 64;

    __shared__ __attribute__((aligned(16))) bf16 As[64][72];
    __shared__ __attribute__((aligned(16))) bf16 Bs[64][72];

    const int r0 = t >> 2;
    const int c0 = (t & 3) * 16;
    const int arow = m0 + r0;
    const float* bptr = wo + (size_t)(n0 + r0) * DM + c0;

    bf16x8 ca0 = combineA(o0, o1, lsum, arow, c0);
    bf16x8 ca1 = combineA(o0, o1, lsum, arow, c0 + 8);
    f32x4 wv0 = *(const f32x4*)(bptr);
    f32x4 wv1 = *(const f32x4*)(bptr + 4);
    f32x4 wv2 = *(const f32x4*)(bptr + 8);
    f32x4 wv3 = *(const f32x4*)(bptr + 12);

    f32x4 acc[2][2];
    #pragma unroll
    for (int mi = 0; mi < 2; mi++)
        #pragma unroll
        for (int ni = 0; ni < 2; ni++) acc[mi][ni] = (f32x4){0.f, 0.f, 0.f, 0.f};

    for (int kk = 0; kk < DM; kk += 64) {
        __syncthreads();
        *(bf16x8*)&As[r0][c0]     = ca0;
        *(bf16x8*)&As[r0][c0 + 8] = ca1;
        {
            bf16x8 b0v, b1v;
            #pragma unroll
            for (int j = 0; j < 4; j++) {
                b0v[j] = (bf16)wv0[j]; b0v[4 + j] = (bf16)wv1[j];
                b1v[j] = (bf16)wv2[j]; b1v[4 + j] = (bf16)wv3[j];
            }
            *(bf16x8*)&Bs[r0][c0]     = b0v;
            *(bf16x8*)&Bs[r0][c0 + 8] = b1v;
        }
        __syncthreads();
        if (kk + 64 < DM) {
            ca0 = combineA(o0, o1, lsum, arow, kk + 64 + c0);
            ca1 = combineA(o0, o1, lsum, arow, kk + 64 + c0 + 8);
            wv0 = *(const f32x4*)(bptr + kk + 64);
            wv1 = *(const f32x4*)(bptr + kk + 64 + 4);
            wv2 = *(const f32x4*)(bptr + kk + 64 + 8);
            wv3 = *(const f32x4*)(bptr + kk + 64 + 12);
        }

        #pragma unroll
        for (int kc = 0; kc < 64; kc += 32) {
            bf16x8 af[2], bf[2];
            #pragma unroll
            for (int mi = 0; mi < 2; mi++)
                af[mi] = *(const bf16x8*)&As[wr * 32 + mi * 16 + l15][kc + quad * 8];
            #pragma unroll
            for (int ni = 0; ni < 2; ni++)
                bf[ni] = *(const bf16x8*)&Bs[wc * 32 + ni * 16 + l15][kc + quad * 8];
            #pragma unroll
            for (int mi = 0; mi < 2; mi++)
                #pragma unroll
                for (int ni = 0; ni < 2; ni++)
                    acc[mi][ni] = __builtin_amdgcn_mfma_f32_16x16x32_bf16(af[mi], bf[ni], acc[mi][ni], 0, 0, 0);
        }
    }

    #pragma unroll
    for (int ni = 0; ni < 2; ni++) {
        int col = n0 + wc * 32 + ni * 16 + l15;
        float bb = bo[col];
        #pragma unroll
        for (int mi = 0; mi < 2; mi++) {
            #pragma unroll
            for (int r = 0; r < 4; r++) {
                size_t idx = (size_t)(m0 + wr * 32 + mi * 16 + quad * 4 + r) * DM + col;
                float val = ldT(xin, idx, f32in) + acc[mi][ni][r] + bb;
                if (f32out) ((float*)xout)[idx] = val;
                else        ((bf16*)xout)[idx] = (bf16)val;
            }
        }
    }
}

// ---------------------------------------------------------------------------
// Flash attention — Q-tile 128 (2 q-groups/wave), split-KV x2, KV tile 128
// (round-16 proven, byte-identical).
// ---------------------------------------------------------------------------
__global__ __launch_bounds__(256, 3) void attn_kernel(
    const bf16* __restrict__ q, const bf16* __restrict__ k, const bf16* __restrict__ vt,
    bf16* __restrict__ o0, bf16* __restrict__ o1, float* __restrict__ lsum)
{
    int qt = blockIdx.x, h = blockIdx.y;
    int b = blockIdx.z >> 1, split = blockIdx.z & 1;
    int wave = threadIdx.x >> 6, lane = threadIdx.x & 63;
    int l15 = lane & 15, quad = lane >> 4;
    int q0 = qt * 128;
    const int kvbase = split * (SEQ / 2);
    size_t basebh = (size_t)b * SEQ * DM + (size_t)h * DK;

    __shared__ __attribute__((aligned(16))) bf16 KsP0[128][72];   // Ks; qg0's P aliases
    __shared__ __attribute__((aligned(16))) bf16 Vt[64][136];     // V^T [d][kv]
    __shared__ __attribute__((aligned(16))) bf16 P1[4][16][136];  // qg1's P (dedicated)
    bf16 (*P0)[16][136] = (bf16 (*)[16][136])&KsP0[0][0];

    bf16x8 aq[2][2];
    #pragma unroll
    for (int qg = 0; qg < 2; qg++) {
        const bf16* qp = q + basebh + (size_t)(q0 + qg * 64 + wave * 16 + l15) * DM + quad * 8;
        aq[qg][0] = *(const bf16x8*)(qp);
        aq[qg][1] = *(const bf16x8*)(qp + 32);
    }

    const float c2 = 0.18033688011112042f;   // log2(e)/8
    float lr[2][2] = {{0.f, 0.f}, {0.f, 0.f}};
    f32x4 oacc[2][4];
    #pragma unroll
    for (int qg = 0; qg < 2; qg++)
        #pragma unroll
        for (int mt = 0; mt < 4; mt++) oacc[qg][mt] = (f32x4){0.f, 0.f, 0.f, 0.f};

    const int sd  = threadIdx.x >> 2;
    const int sk0 = (threadIdx.x & 3) * 32;
    const bf16* vtrow0 = vt + (((size_t)b * NH + h) * DK + sd) * SEQ + sk0;
    const int skk = threadIdx.x >> 1;
    const int sdk = (threadIdx.x & 1) * 32;
    const bf16* krow0 = k + basebh + (size_t)skk * DM + sdk;

    bf16x8 vr0 = *(const bf16x8*)(vtrow0 + kvbase);
    bf16x8 vr1 = *(const bf16x8*)(vtrow0 + kvbase + 8);
    bf16x8 vr2 = *(const bf16x8*)(vtrow0 + kvbase + 16);
    bf16x8 vr3 = *(const bf16x8*)(vtrow0 + kvbase + 24);
    bf16x8 kr0 = *(const bf16x8*)(krow0 + (size_t)kvbase * DM);
    bf16x8 kr1 = *(const bf16x8*)(krow0 + (size_t)kvbase * DM + 8);
    bf16x8 kr2 = *(const bf16x8*)(krow0 + (size_t)kvbase * DM + 16);
    bf16x8 kr3 = *(const bf16x8*)(krow0 + (size_t)kvbase * DM + 24);

    for (int it = 0; it < 16; it++) {
        __syncthreads();   // barrier A
        *(bf16x8*)&Vt[sd][sk0]      = vr0;
        *(bf16x8*)&Vt[sd][sk0 + 8]  = vr1;
        *(bf16x8*)&Vt[sd][sk0 + 16] = vr2;
        *(bf16x8*)&Vt[sd][sk0 + 24] = vr3;
        *(bf16x8*)&KsP0[skk][sdk]      = kr0;
        *(bf16x8*)&KsP0[skk][sdk + 8]  = kr1;
        *(bf16x8*)&KsP0[skk][sdk + 16] = kr2;
        *(bf16x8*)&KsP0[skk][sdk + 24] = kr3;
        __syncthreads();   // barrier B

        {   // prefetch next tile: drains at next barrier A
            int kvn = (it + 1 < 16) ? kvbase + (it + 1) * 128 : kvbase;
            const bf16* vp = vtrow0 + kvn;
            vr0 = *(const bf16x8*)(vp);
            vr1 = *(const bf16x8*)(vp + 8);
            vr2 = *(const bf16x8*)(vp + 16);
            vr3 = *(const bf16x8*)(vp + 24);
            const bf16* kp2 = krow0 + (size_t)kvn * DM;
            kr0 = *(const bf16x8*)(kp2);
            kr1 = *(const bf16x8*)(kp2 + 8);
            kr2 = *(const bf16x8*)(kp2 + 16);
            kr3 = *(const bf16x8*)(kp2 + 24);
        }

        bf16x4 pk0[8];
        #pragma unroll
        for (int g = 0; g < 8; g++) {
            bf16x8 kf0 = *(const bf16x8*)&KsP0[g * 16 + l15][quad * 8];
            bf16x8 kf1 = *(const bf16x8*)&KsP0[g * 16 + l15][quad * 8 + 32];
            f32x4 s0 = (f32x4){0.f, 0.f, 0.f, 0.f};
            f32x4 s1 = (f32x4){0.f, 0.f, 0.f, 0.f};
            s0 = __builtin_amdgcn_mfma_f32_16x16x32_bf16(kf0, aq[0][0], s0, 0, 0, 0);
            s1 = __builtin_amdgcn_mfma_f32_16x16x32_bf16(kf0, aq[1][0], s1, 0, 0, 0);
            s0 = __builtin_amdgcn_mfma_f32_16x16x32_bf16(kf1, aq[0][1], s0, 0, 0, 0);
            s1 = __builtin_amdgcn_mfma_f32_16x16x32_bf16(kf1, aq[1][1], s1, 0, 0, 0);
            bf16x4 t1;
            #pragma unroll
            for (int r = 0; r < 4; r++) {
                float p0 = __builtin_amdgcn_exp2f(s0[r] * c2);
                float p1 = __builtin_amdgcn_exp2f(s1[r] * c2);
                lr[0][r & 1] += p0;
                lr[1][r & 1] += p1;
                pk0[g][r] = (bf16)p0;
                t1[r] = (bf16)p1;
            }
            *(bf16x4*)&P1[wave][l15][g * 16 + quad * 4] = t1;
        }

        __syncthreads();   // barrier C: Ks reads done before aliased P0 writes

        #pragma unroll
        for (int g = 0; g < 8; g++)
            *(bf16x4*)&P0[wave][l15][g * 16 + quad * 4] = pk0[g];

        #pragma unroll
        for (int c = 0; c < 4; c++) {
            bf16x8 bp0 = *(const bf16x8*)(&P0[wave][l15][c * 32 + quad * 8]);
            bf16x8 bp1 = *(const bf16x8*)(&P1[wave][l15][c * 32 + quad * 8]);
            #pragma unroll
            for (int mt = 0; mt < 4; mt++) {
                bf16x8 av = *(const bf16x8*)(&Vt[mt * 16 + l15][c * 32 + quad * 8]);
                oacc[0][mt] = __builtin_amdgcn_mfma_f32_16x16x32_bf16(av, bp0, oacc[0][mt], 0, 0, 0);
                oacc[1][mt] = __builtin_amdgcn_mfma_f32_16x16x32_bf16(av, bp1, oacc[1][mt], 0, 0, 0);
            }
        }
    }

    bf16* osel = split ? o1 : o0;
    #pragma unroll
    for (int qg = 0; qg < 2; qg++) {
        float lrun = lr[qg][0] + lr[qg][1];
        lrun += __shfl_xor(lrun, 16);
        lrun += __shfl_xor(lrun, 32);
        int row = q0 + qg * 64 + wave * 16 + l15;
        bf16* op = osel + basebh + (size_t)row * DM + quad * 4;
        #pragma unroll
        for (int mt = 0; mt < 4; mt++) {
            bf16x4 ov;
            #pragma unroll
            for (int r = 0; r < 4; r++) ov[r] = (bf16)oacc[qg][mt][r];
            *(bf16x4*)(op + mt * 16) = ov;
        }
        if (quad == 0)
            lsum[(size_t)split * (NB * NH * SEQ) + ((size_t)b * NH + h) * SEQ + row] = lrun;
    }
}

// ---------------------------------------------------------------------------
extern "C" void kernel_launch(void* const* d_in, const int* in_sizes, int n_in,
                              void* d_out, int out_size, void* d_ws, size_t ws_size,
                              hipStream_t stream) {
    const size_t SZ = (size_t)NB * SEQ * DM;

    const float* x   = (const float*)d_in[0];
    const float* a0  = (const float*)d_in[1];
    const float* b0  = (const float*)d_in[2];
    const float* ra0 = (const float*)d_in[3];
    const float* rb0 = (const float*)d_in[4];
    const float* ra1 = (const float*)d_in[5];
    const float* rb1 = (const float*)d_in[6];
    const float* wq  = (const float*)d_in[7];  const float* bq = (const float*)d_in[8];
    const float* wk  = (const float*)d_in[9];  const float* bk = (const float*)d_in[10];
    const float* wv  = (const float*)d_in[11]; const float* bv = (const float*)d_in[12];
    const float* wo  = (const float*)d_in[13]; const float* bo = (const float*)d_in[14];

    bf16* zob = (bf16*)d_ws;     // z, then attn O~ split-0
    bf16* qb  = zob + SZ;
    bf16* kb  = qb + SZ;
    bf16* vtb = kb + SZ;         // V^T [NB][NH][DK][SEQ]
    bf16* x1  = vtb + SZ;
    bf16* o1b = x1 + SZ;         // attn O~ split-1
    float* lsum = (float*)(o1b + SZ);  // [2][NB][NH][SEQ] f32

    dim3 gLN(NB * SEQ / 4);
    dim3 gG(NB * SEQ / 128, DM / 128, 3);
    dim3 gP(NB * SEQ / 64, DM / 64);
    dim3 gA(SEQ / 128, NH, NB * 2);

    // pass 1
    ln2_kernel<<<gLN, 256, 0, stream>>>(x, 1, ra0, rb0, a0, b0, zob);
    qkv_kernel<<<gG, 256, 0, stream>>>(zob, wq, wk, wv, bq, bk, bv, qb, vtb);
    attn_kernel<<<gA, 256, 0, stream>>>(qb, kb, vtb, zob, o1b, lsum);
    proj_kernel<<<gP, 256, 0, stream>>>(zob, o1b, lsum, wo, bo, x, 1, x1, 0);
    // pass 2
    ln2_kernel<<<gLN, 256, 0, stream>>>(x1, 0, ra1, rb1, a0, b0, zob);
    qkv_kernel<<<gG, 256, 0, stream>>>(zob, wq, wk, wv, bq, bk, bv, qb, vtb);
    attn_kernel<<<gA, 256, 0, stream>>>(qb, kb, vtb, zob, o1b, lsum);
    proj_kernel<<<gP, 256, 0, stream>>>(zob, o1b, lsum, wo, bo, x1, 0, d_out, 1);
}

// Round 18
// 314.444 us; speedup vs baseline: 1.0114x; 1.0114x over previous
//
#include <hip/hip_runtime.h>
#include <hip/hip_bf16.h>
#include <math.h>

typedef __bf16 bf16;
typedef __bf16 bf16x2 __attribute__((ext_vector_type(2)));
typedef __bf16 bf16x4 __attribute__((ext_vector_type(4)));
typedef __bf16 bf16x8 __attribute__((ext_vector_type(8)));
typedef float  f32x2  __attribute__((ext_vector_type(2)));
typedef float  f32x4  __attribute__((ext_vector_type(4)));

#define SEQ 4096
#define DM  384
#define NH  6
#define DK  64
#define NB  2
#define WN  (DM * DM)
#define EPSLN 1e-6f

// dual-dtype scalar load: f32 ? float : bf16   (flag is a VALUE, wave-uniform)
__device__ __forceinline__ float ldT(const void* p, size_t i, int f32) {
    return f32 ? ((const float*)p)[i] : (float)(((const bf16*)p)[i]);
}

// ---------------------------------------------------------------------------
// z = LN(LN(x, ra, rb), a0, b0)  — torch style: unbiased std, /(std+eps)
// Paired (x2) vector loads (round-17, kept).
// ---------------------------------------------------------------------------
__global__ __launch_bounds__(256) void ln2_kernel(
    const void* __restrict__ x, int xf32,
    const float* __restrict__ ra, const float* __restrict__ rb,
    const float* __restrict__ a0, const float* __restrict__ b0, bf16* __restrict__ z)
{
    int row  = blockIdx.x * 4 + (threadIdx.x >> 6);
    int lane = threadIdx.x & 63;
    size_t base = (size_t)row * DM;

    float v[6];
    float s = 0.f;
    #pragma unroll
    for (int i = 0; i < 3; i++) {
        int c = lane * 2 + i * 128;
        float t0, t1;
        if (xf32) {
            f32x2 t = *(const f32x2*)((const float*)x + base + c);
            t0 = t[0]; t1 = t[1];
        } else {
            bf16x2 u = *(const bf16x2*)((const bf16*)x + base + c);
            t0 = (float)u[0]; t1 = (float)u[1];
        }
        v[2 * i] = t0; v[2 * i + 1] = t1; s += t0 + t1;
    }
    #pragma unroll
    for (int off = 1; off < 64; off <<= 1) s += __shfl_xor(s, off);
    float m = s * (1.f / DM);
    float sq = 0.f;
    #pragma unroll
    for (int i = 0; i < 6; i++) { float d = v[i] - m; sq += d * d; }
    #pragma unroll
    for (int off = 1; off < 64; off <<= 1) sq += __shfl_xor(sq, off);
    float inv = 1.f / (sqrtf(sq * (1.f / (DM - 1))) + EPSLN);

    s = 0.f;
    #pragma unroll
    for (int i = 0; i < 3; i++) {
        int c = lane * 2 + i * 128;
        f32x2 rav = *(const f32x2*)(ra + c);
        f32x2 rbv = *(const f32x2*)(rb + c);
        v[2 * i]     = rav[0] * (v[2 * i] - m) * inv + rbv[0];
        v[2 * i + 1] = rav[1] * (v[2 * i + 1] - m) * inv + rbv[1];
        s += v[2 * i] + v[2 * i + 1];
    }
    #pragma unroll
    for (int off = 1; off < 64; off <<= 1) s += __shfl_xor(s, off);
    m = s * (1.f / DM);
    sq = 0.f;
    #pragma unroll
    for (int i = 0; i < 6; i++) { float d = v[i] - m; sq += d * d; }
    #pragma unroll
    for (int off = 1; off < 64; off <<= 1) sq += __shfl_xor(sq, off);
    inv = 1.f / (sqrtf(sq * (1.f / (DM - 1))) + EPSLN);

    bf16* zr = z + base;
    #pragma unroll
    for (int i = 0; i < 3; i++) {
        int c = lane * 2 + i * 128;
        f32x2 a0v = *(const f32x2*)(a0 + c);
        f32x2 b0v = *(const f32x2*)(b0 + c);
        bf16x2 o;
        o[0] = (bf16)(a0v[0] * (v[2 * i] - m) * inv + b0v[0]);
        o[1] = (bf16)(a0v[1] * (v[2 * i + 1] - m) * inv + b0v[1]);
        *(bf16x2*)(zr + c) = o;
    }
}

// ---------------------------------------------------------------------------
// qkv GEMM, LDS-staged, BM=128 BN=64 BK=64 (round-16 proven config).
// grid (64,6,3)=1152 = 4.5 blocks/CU. Weights f32, converted during staging.
// z=0->q, z=1->k, z=2->V^T [b][h][d][s]. Prefetch AFTER barrier B.
// ---------------------------------------------------------------------------
__global__ __launch_bounds__(256) void qkv_kernel(
    const bf16* __restrict__ A,
    const float* __restrict__ wq, const float* __restrict__ wk, const float* __restrict__ wv,
    const float* __restrict__ bq, const float* __restrict__ bk, const float* __restrict__ bv,
    bf16* __restrict__ qkout, bf16* __restrict__ vt)
{
    const int z = blockIdx.z;
    const float* W    = (z == 0) ? wq : (z == 1) ? wk : wv;
    const float* bias = (z == 0) ? bq : (z == 1) ? bk : bv;

    const int t = threadIdx.x;
    const int wave = t >> 6, lane = t & 63;
    const int l15 = lane & 15, quad = lane >> 4;
    const int wr = wave >> 1, wc = wave & 1;
    const int m0 = blockIdx.x * 128;
    const int n0 = blockIdx.y * 64;

    __shared__ __attribute__((aligned(16))) bf16 As[128][72];
    __shared__ __attribute__((aligned(16))) bf16 Bs[64][72];

    const int r0 = t >> 2;            // 0..63
    const int c0 = (t & 3) * 16;      // 0,16,32,48

    const bf16*  aptr0 = A + (size_t)(m0 + r0) * DM + c0;
    const bf16*  aptr1 = A + (size_t)(m0 + 64 + r0) * DM + c0;
    const float* bptr  = W + (size_t)(n0 + r0) * DM + c0;

    bf16x8 ra00 = *(const bf16x8*)(aptr0);
    bf16x8 ra01 = *(const bf16x8*)(aptr0 + 8);
    bf16x8 ra10 = *(const bf16x8*)(aptr1);
    bf16x8 ra11 = *(const bf16x8*)(aptr1 + 8);
    f32x4 wv0 = *(const f32x4*)(bptr);
    f32x4 wv1 = *(const f32x4*)(bptr + 4);
    f32x4 wv2 = *(const f32x4*)(bptr + 8);
    f32x4 wv3 = *(const f32x4*)(bptr + 12);

    f32x4 acc[4][2];
    #pragma unroll
    for (int mi = 0; mi < 4; mi++)
        #pragma unroll
        for (int ni = 0; ni < 2; ni++) acc[mi][ni] = (f32x4){0.f, 0.f, 0.f, 0.f};

    for (int kk = 0; kk < DM; kk += 64) {
        __syncthreads();   // barrier A (drains prev prefetch — hidden)
        *(bf16x8*)&As[r0][c0]          = ra00;
        *(bf16x8*)&As[r0][c0 + 8]      = ra01;
        *(bf16x8*)&As[64 + r0][c0]     = ra10;
        *(bf16x8*)&As[64 + r0][c0 + 8] = ra11;
        {
            bf16x8 b0v, b1v;
            #pragma unroll
            for (int j = 0; j < 4; j++) {
                b0v[j] = (bf16)wv0[j]; b0v[4 + j] = (bf16)wv1[j];
                b1v[j] = (bf16)wv2[j]; b1v[4 + j] = (bf16)wv3[j];
            }
            *(bf16x8*)&Bs[r0][c0]     = b0v;
            *(bf16x8*)&Bs[r0][c0 + 8] = b1v;
        }
        __syncthreads();   // barrier B
        if (kk + 64 < DM) {   // prefetch next K-tile, drains at next barrier A
            ra00 = *(const bf16x8*)(aptr0 + kk + 64);
            ra01 = *(const bf16x8*)(aptr0 + kk + 64 + 8);
            ra10 = *(const bf16x8*)(aptr1 + kk + 64);
            ra11 = *(const bf16x8*)(aptr1 + kk + 64 + 8);
            wv0 = *(const f32x4*)(bptr + kk + 64);
            wv1 = *(const f32x4*)(bptr + kk + 64 + 4);
            wv2 = *(const f32x4*)(bptr + kk + 64 + 8);
            wv3 = *(const f32x4*)(bptr + kk + 64 + 12);
        }

        #pragma unroll
        for (int kc = 0; kc < 64; kc += 32) {
            bf16x8 af[4], bf[2];
            #pragma unroll
            for (int mi = 0; mi < 4; mi++)
                af[mi] = *(const bf16x8*)&As[wr * 64 + mi * 16 + l15][kc + quad * 8];
            #pragma unroll
            for (int ni = 0; ni < 2; ni++)
                bf[ni] = *(const bf16x8*)&Bs[wc * 32 + ni * 16 + l15][kc + quad * 8];
            #pragma unroll
            for (int mi = 0; mi < 4; mi++)
                #pragma unroll
                for (int ni = 0; ni < 2; ni++)
                    acc[mi][ni] = __builtin_amdgcn_mfma_f32_16x16x32_bf16(af[mi], bf[ni], acc[mi][ni], 0, 0, 0);
        }
    }

    if (z < 2) {
        bf16* out = qkout + (size_t)z * ((size_t)NB * SEQ * DM);
        #pragma unroll
        for (int ni = 0; ni < 2; ni++) {
            int col = n0 + wc * 32 + ni * 16 + l15;
            float bb = bias[col];
            #pragma unroll
            for (int mi = 0; mi < 4; mi++) {
                #pragma unroll
                for (int r = 0; r < 4; r++) {
                    int row = m0 + wr * 64 + mi * 16 + quad * 4 + r;
                    out[(size_t)row * DM + col] = (bf16)(acc[mi][ni][r] + bb);
                }
            }
        }
    } else {
        #pragma unroll
        for (int ni = 0; ni < 2; ni++) {
            int col = n0 + wc * 32 + ni * 16 + l15;
            int h = col >> 6, d = col & 63;
            float bb = bias[col];
            #pragma unroll
            for (int mi = 0; mi < 4; mi++) {
                int row0 = m0 + wr * 64 + mi * 16 + quad * 4;
                int b = row0 >> 12, s0 = row0 & (SEQ - 1);
                bf16x4 ov;
                #pragma unroll
                for (int r = 0; r < 4; r++) ov[r] = (bf16)(acc[mi][ni][r] + bb);
                *(bf16x4*)(vt + (((size_t)b * NH + h) * DK + d) * SEQ + s0) = ov;
            }
        }
    }
}

// ---------------------------------------------------------------------------
// proj GEMM, BK=64, fused split reduce (round-15 proven, byte-identical).
// ---------------------------------------------------------------------------
__device__ __forceinline__ bf16x8 combineA(
    const bf16* __restrict__ o0, const bf16* __restrict__ o1,
    const float* __restrict__ lsum, int row, int kcol)
{
    int b = row >> 12, s = row & (SEQ - 1);
    int h = kcol >> 6;
    size_t lidx = ((size_t)b * NH + h) * SEQ + s;
    float inv = 1.f / (lsum[lidx] + lsum[(size_t)(NB * NH * SEQ) + lidx]);
    size_t idx = (size_t)row * DM + kcol;
    bf16x8 a = *(const bf16x8*)(o0 + idx);
    bf16x8 c = *(const bf16x8*)(o1 + idx);
    bf16x8 r;
    #pragma unroll
    for (int j = 0; j < 8; j++) r[j] = (bf16)(((float)a[j] + (float)c[j]) * inv);
    return r;
}

__global__ __launch_bounds__(256) void proj_kernel(
    const bf16* __restrict__ o0, const bf16* __restrict__ o1,
    const float* __restrict__ lsum,
    const float* __restrict__ wo, const float* __restrict__ bo,
    const void* __restrict__ xin, int f32in,
    void* __restrict__ xout, int f32out)
{
    const int t = threadIdx.x;
    const int wave = t >> 6, lane = t & 63;
    const int l15 = lane & 15, quad = lane >> 4;
    const int wr = wave >> 1, wc = wave & 1;
    const int m0 = blockIdx.x * 64;
    const int n0 = blockIdx.y * 64;

    __shared__ __attribute__((aligned(16))) bf16 As[64][72];
    __shared__ __attribute__((aligned(16))) bf16 Bs[64][72];

    const int r0 = t >> 2;
    const int c0 = (t & 3) * 16;
    const int arow = m0 + r0;
    const float* bptr = wo + (size_t)(n0 + r0) * DM + c0;

    bf16x8 ca0 = combineA(o0, o1, lsum, arow, c0);
    bf16x8 ca1 = combineA(o0, o1, lsum, arow, c0 + 8);
    f32x4 wv0 = *(const f32x4*)(bptr);
    f32x4 wv1 = *(const f32x4*)(bptr + 4);
    f32x4 wv2 = *(const f32x4*)(bptr + 8);
    f32x4 wv3 = *(const f32x4*)(bptr + 12);

    f32x4 acc[2][2];
    #pragma unroll
    for (int mi = 0; mi < 2; mi++)
        #pragma unroll
        for (int ni = 0; ni < 2; ni++) acc[mi][ni] = (f32x4){0.f, 0.f, 0.f, 0.f};

    for (int kk = 0; kk < DM; kk += 64) {
        __syncthreads();
        *(bf16x8*)&As[r0][c0]     = ca0;
        *(bf16x8*)&As[r0][c0 + 8] = ca1;
        {
            bf16x8 b0v, b1v;
            #pragma unroll
            for (int j = 0; j < 4; j++) {
                b0v[j] = (bf16)wv0[j]; b0v[4 + j] = (bf16)wv1[j];
                b1v[j] = (bf16)wv2[j]; b1v[4 + j] = (bf16)wv3[j];
            }
            *(bf16x8*)&Bs[r0][c0]     = b0v;
            *(bf16x8*)&Bs[r0][c0 + 8] = b1v;
        }
        __syncthreads();
        if (kk + 64 < DM) {
            ca0 = combineA(o0, o1, lsum, arow, kk + 64 + c0);
            ca1 = combineA(o0, o1, lsum, arow, kk + 64 + c0 + 8);
            wv0 = *(const f32x4*)(bptr + kk + 64);
            wv1 = *(const f32x4*)(bptr + kk + 64 + 4);
            wv2 = *(const f32x4*)(bptr + kk + 64 + 8);
            wv3 = *(const f32x4*)(bptr + kk + 64 + 12);
        }

        #pragma unroll
        for (int kc = 0; kc < 64; kc += 32) {
            bf16x8 af[2], bf[2];
            #pragma unroll
            for (int mi = 0; mi < 2; mi++)
                af[mi] = *(const bf16x8*)&As[wr * 32 + mi * 16 + l15][kc + quad * 8];
            #pragma unroll
            for (int ni = 0; ni < 2; ni++)
                bf[ni] = *(const bf16x8*)&Bs[wc * 32 + ni * 16 + l15][kc + quad * 8];
            #pragma unroll
            for (int mi = 0; mi < 2; mi++)
                #pragma unroll
                for (int ni = 0; ni < 2; ni++)
                    acc[mi][ni] = __builtin_amdgcn_mfma_f32_16x16x32_bf16(af[mi], bf[ni], acc[mi][ni], 0, 0, 0);
        }
    }

    #pragma unroll
    for (int ni = 0; ni < 2; ni++) {
        int col = n0 + wc * 32 + ni * 16 + l15;
        float bb = bo[col];
        #pragma unroll
        for (int mi = 0; mi < 2; mi++) {
            #pragma unroll
            for (int r = 0; r < 4; r++) {
                size_t idx = (size_t)(m0 + wr * 32 + mi * 16 + quad * 4 + r) * DM + col;
                float val = ldT(xin, idx, f32in) + acc[mi][ni][r] + bb;
                if (f32out) ((float*)xout)[idx] = val;
                else        ((bf16*)xout)[idx] = (bf16)val;
            }
        }
    }
}

// ---------------------------------------------------------------------------
// Flash attention — Q-tile 128 (2 q-groups/wave), split-KV x2, KV tile 128
// (round-16 proven, byte-identical).
// ---------------------------------------------------------------------------
__global__ __launch_bounds__(256, 3) void attn_kernel(
    const bf16* __restrict__ q, const bf16* __restrict__ k, const bf16* __restrict__ vt,
    bf16* __restrict__ o0, bf16* __restrict__ o1, float* __restrict__ lsum)
{
    int qt = blockIdx.x, h = blockIdx.y;
    int b = blockIdx.z >> 1, split = blockIdx.z & 1;
    int wave = threadIdx.x >> 6, lane = threadIdx.x & 63;
    int l15 = lane & 15, quad = lane >> 4;
    int q0 = qt * 128;
    const int kvbase = split * (SEQ / 2);
    size_t basebh = (size_t)b * SEQ * DM + (size_t)h * DK;

    __shared__ __attribute__((aligned(16))) bf16 KsP0[128][72];   // Ks; qg0's P aliases
    __shared__ __attribute__((aligned(16))) bf16 Vt[64][136];     // V^T [d][kv]
    __shared__ __attribute__((aligned(16))) bf16 P1[4][16][136];  // qg1's P (dedicated)
    bf16 (*P0)[16][136] = (bf16 (*)[16][136])&KsP0[0][0];

    bf16x8 aq[2][2];
    #pragma unroll
    for (int qg = 0; qg < 2; qg++) {
        const bf16* qp = q + basebh + (size_t)(q0 + qg * 64 + wave * 16 + l15) * DM + quad * 8;
        aq[qg][0] = *(const bf16x8*)(qp);
        aq[qg][1] = *(const bf16x8*)(qp + 32);
    }

    const float c2 = 0.18033688011112042f;   // log2(e)/8
    float lr[2][2] = {{0.f, 0.f}, {0.f, 0.f}};
    f32x4 oacc[2][4];
    #pragma unroll
    for (int qg = 0; qg < 2; qg++)
        #pragma unroll
        for (int mt = 0; mt < 4; mt++) oacc[qg][mt] = (f32x4){0.f, 0.f, 0.f, 0.f};

    const int sd  = threadIdx.x >> 2;
    const int sk0 = (threadIdx.x & 3) * 32;
    const bf16* vtrow0 = vt + (((size_t)b * NH + h) * DK + sd) * SEQ + sk0;
    const int skk = threadIdx.x >> 1;
    const int sdk = (threadIdx.x & 1) * 32;
    const bf16* krow0 = k + basebh + (size_t)skk * DM + sdk;

    bf16x8 vr0 = *(const bf16x8*)(vtrow0 + kvbase);
    bf16x8 vr1 = *(const bf16x8*)(vtrow0 + kvbase + 8);
    bf16x8 vr2 = *(const bf16x8*)(vtrow0 + kvbase + 16);
    bf16x8 vr3 = *(const bf16x8*)(vtrow0 + kvbase + 24);
    bf16x8 kr0 = *(const bf16x8*)(krow0 + (size_t)kvbase * DM);
    bf16x8 kr1 = *(const bf16x8*)(krow0 + (size_t)kvbase * DM + 8);
    bf16x8 kr2 = *(const bf16x8*)(krow0 + (size_t)kvbase * DM + 16);
    bf16x8 kr3 = *(const bf16x8*)(krow0 + (size_t)kvbase * DM + 24);

    for (int it = 0; it < 16; it++) {
        __syncthreads();   // barrier A
        *(bf16x8*)&Vt[sd][sk0]      = vr0;
        *(bf16x8*)&Vt[sd][sk0 + 8]  = vr1;
        *(bf16x8*)&Vt[sd][sk0 + 16] = vr2;
        *(bf16x8*)&Vt[sd][sk0 + 24] = vr3;
        *(bf16x8*)&KsP0[skk][sdk]      = kr0;
        *(bf16x8*)&KsP0[skk][sdk + 8]  = kr1;
        *(bf16x8*)&KsP0[skk][sdk + 16] = kr2;
        *(bf16x8*)&KsP0[skk][sdk + 24] = kr3;
        __syncthreads();   // barrier B

        {   // prefetch next tile: drains at next barrier A
            int kvn = (it + 1 < 16) ? kvbase + (it + 1) * 128 : kvbase;
            const bf16* vp = vtrow0 + kvn;
            vr0 = *(const bf16x8*)(vp);
            vr1 = *(const bf16x8*)(vp + 8);
            vr2 = *(const bf16x8*)(vp + 16);
            vr3 = *(const bf16x8*)(vp + 24);
            const bf16* kp2 = krow0 + (size_t)kvn * DM;
            kr0 = *(const bf16x8*)(kp2);
            kr1 = *(const bf16x8*)(kp2 + 8);
            kr2 = *(const bf16x8*)(kp2 + 16);
            kr3 = *(const bf16x8*)(kp2 + 24);
        }

        bf16x4 pk0[8];
        #pragma unroll
        for (int g = 0; g < 8; g++) {
            bf16x8 kf0 = *(const bf16x8*)&KsP0[g * 16 + l15][quad * 8];
            bf16x8 kf1 = *(const bf16x8*)&KsP0[g * 16 + l15][quad * 8 + 32];
            f32x4 s0 = (f32x4){0.f, 0.f, 0.f, 0.f};
            f32x4 s1 = (f32x4){0.f, 0.f, 0.f, 0.f};
            s0 = __builtin_amdgcn_mfma_f32_16x16x32_bf16(kf0, aq[0][0], s0, 0, 0, 0);
            s1 = __builtin_amdgcn_mfma_f32_16x16x32_bf16(kf0, aq[1][0], s1, 0, 0, 0);
            s0 = __builtin_amdgcn_mfma_f32_16x16x32_bf16(kf1, aq[0][1], s0, 0, 0, 0);
            s1 = __builtin_amdgcn_mfma_f32_16x16x32_bf16(kf1, aq[1][1], s1, 0, 0, 0);
            bf16x4 t1;
            #pragma unroll
            for (int r = 0; r < 4; r++) {
                float p0 = __builtin_amdgcn_exp2f(s0[r] * c2);
                float p1 = __builtin_amdgcn_exp2f(s1[r] * c2);
                lr[0][r & 1] += p0;
                lr[1][r & 1] += p1;
                pk0[g][r] = (bf16)p0;
                t1[r] = (bf16)p1;
            }
            *(bf16x4*)&P1[wave][l15][g * 16 + quad * 4] = t1;
        }

        __syncthreads();   // barrier C: Ks reads done before aliased P0 writes

        #pragma unroll
        for (int g = 0; g < 8; g++)
            *(bf16x4*)&P0[wave][l15][g * 16 + quad * 4] = pk0[g];

        #pragma unroll
        for (int c = 0; c < 4; c++) {
            bf16x8 bp0 = *(const bf16x8*)(&P0[wave][l15][c * 32 + quad * 8]);
            bf16x8 bp1 = *(const bf16x8*)(&P1[wave][l15][c * 32 + quad * 8]);
            #pragma unroll
            for (int mt = 0; mt < 4; mt++) {
                bf16x8 av = *(const bf16x8*)(&Vt[mt * 16 + l15][c * 32 + quad * 8]);
                oacc[0][mt] = __builtin_amdgcn_mfma_f32_16x16x32_bf16(av, bp0, oacc[0][mt], 0, 0, 0);
                oacc[1][mt] = __builtin_amdgcn_mfma_f32_16x16x32_bf16(av, bp1, oacc[1][mt], 0, 0, 0);
            }
        }
    }

    bf16* osel = split ? o1 : o0;
    #pragma unroll
    for (int qg = 0; qg < 2; qg++) {
        float lrun = lr[qg][0] + lr[qg][1];
        lrun += __shfl_xor(lrun, 16);
        lrun += __shfl_xor(lrun, 32);
        int row = q0 + qg * 64 + wave * 16 + l15;
        bf16* op = osel + basebh + (size_t)row * DM + quad * 4;
        #pragma unroll
        for (int mt = 0; mt < 4; mt++) {
            bf16x4 ov;
            #pragma unroll
            for (int r = 0; r < 4; r++) ov[r] = (bf16)oacc[qg][mt][r];
            *(bf16x4*)(op + mt * 16) = ov;
        }
        if (quad == 0)
            lsum[(size_t)split * (NB * NH * SEQ) + ((size_t)b * NH + h) * SEQ + row] = lrun;
    }
}

// ---------------------------------------------------------------------------
extern "C" void kernel_launch(void* const* d_in, const int* in_sizes, int n_in,
                              void* d_out, int out_size, void* d_ws, size_t ws_size,
                              hipStream_t stream) {
    const size_t SZ = (size_t)NB * SEQ * DM;

    const float* x   = (const float*)d_in[0];
    const float* a0  = (const float*)d_in[1];
    const float* b0  = (const float*)d_in[2];
    const float* ra0 = (const float*)d_in[3];
    const float* rb0 = (const float*)d_in[4];
    const float* ra1 = (const float*)d_in[5];
    const float* rb1 = (const float*)d_in[6];
    const float* wq  = (const float*)d_in[7];  const float* bq = (const float*)d_in[8];
    const float* wk  = (const float*)d_in[9];  const float* bk = (const float*)d_in[10];
    const float* wv  = (const float*)d_in[11]; const float* bv = (const float*)d_in[12];
    const float* wo  = (const float*)d_in[13]; const float* bo = (const float*)d_in[14];

    bf16* zob = (bf16*)d_ws;     // z, then attn O~ split-0
    bf16* qb  = zob + SZ;
    bf16* kb  = qb + SZ;
    bf16* vtb = kb + SZ;         // V^T [NB][NH][DK][SEQ]
    bf16* x1  = vtb + SZ;
    bf16* o1b = x1 + SZ;         // attn O~ split-1
    float* lsum = (float*)(o1b + SZ);  // [2][NB][NH][SEQ] f32

    dim3 gLN(NB * SEQ / 4);
    dim3 gG(NB * SEQ / 128, DM / 64, 3);
    dim3 gP(NB * SEQ / 64, DM / 64);
    dim3 gA(SEQ / 128, NH, NB * 2);

    // pass 1
    ln2_kernel<<<gLN, 256, 0, stream>>>(x, 1, ra0, rb0, a0, b0, zob);
    qkv_kernel<<<gG, 256, 0, stream>>>(zob, wq, wk, wv, bq, bk, bv, qb, vtb);
    attn_kernel<<<gA, 256, 0, stream>>>(qb, kb, vtb, zob, o1b, lsum);
    proj_kernel<<<gP, 256, 0, stream>>>(zob, o1b, lsum, wo, bo, x, 1, x1, 0);
    // pass 2
    ln2_kernel<<<gLN, 256, 0, stream>>>(x1, 0, ra1, rb1, a0, b0, zob);
    qkv_kernel<<<gG, 256, 0, stream>>>(zob, wq, wk, wv, bq, bk, bv, qb, vtb);
    attn_kernel<<<gA, 256, 0, stream>>>(qb, kb, vtb, zob, o1b, lsum);
    proj_kernel<<<gP, 256, 0, stream>>>(zob, o1b, lsum, wo, bo, x1, 0, d_out, 1);
}

// Round 19
// 306.608 us; speedup vs baseline: 1.0372x; 1.0256x over previous
//
#include <hip/hip_runtime.h>
#include <hip/hip_bf16.h>
#include <math.h>

typedef __bf16 bf16;
typedef __bf16 bf16x4 __attribute__((ext_vector_type(4)));
typedef __bf16 bf16x8 __attribute__((ext_vector_type(8)));
typedef float  f32x4  __attribute__((ext_vector_type(4)));

#define SEQ 4096
#define DM  384
#define NH  6
#define DK  64
#define NB  2
#define WN  (DM * DM)
#define EPSLN 1e-6f

// dual-dtype scalar load: f32 ? float : bf16   (flag is a VALUE, wave-uniform)
__device__ __forceinline__ float ldT(const void* p, size_t i, int f32) {
    return f32 ? ((const float*)p)[i] : (float)(((const bf16*)p)[i]);
}

// ---------------------------------------------------------------------------
// z = LN(LN(x, ra, rb), a0, b0)  — torch style: unbiased std, /(std+eps)
// Round-16 scalar-load version (measured best; R17's paired loads were -4us).
// ---------------------------------------------------------------------------
__global__ __launch_bounds__(256) void ln2_kernel(
    const void* __restrict__ x, int xf32,
    const float* __restrict__ ra, const float* __restrict__ rb,
    const float* __restrict__ a0, const float* __restrict__ b0, bf16* __restrict__ z)
{
    int row  = blockIdx.x * 4 + (threadIdx.x >> 6);
    int lane = threadIdx.x & 63;
    size_t base = (size_t)row * DM;

    float v[6];
    float s = 0.f;
    #pragma unroll
    for (int i = 0; i < 6; i++) { v[i] = ldT(x, base + lane + i * 64, xf32); s += v[i]; }
    #pragma unroll
    for (int off = 1; off < 64; off <<= 1) s += __shfl_xor(s, off);
    float m = s * (1.f / DM);
    float sq = 0.f;
    #pragma unroll
    for (int i = 0; i < 6; i++) { float d = v[i] - m; sq += d * d; }
    #pragma unroll
    for (int off = 1; off < 64; off <<= 1) sq += __shfl_xor(sq, off);
    float inv = 1.f / (sqrtf(sq * (1.f / (DM - 1))) + EPSLN);

    s = 0.f;
    #pragma unroll
    for (int i = 0; i < 6; i++) {
        int c = lane + i * 64;
        v[i] = ra[c] * (v[i] - m) * inv + rb[c];
        s += v[i];
    }
    #pragma unroll
    for (int off = 1; off < 64; off <<= 1) s += __shfl_xor(s, off);
    m = s * (1.f / DM);
    sq = 0.f;
    #pragma unroll
    for (int i = 0; i < 6; i++) { float d = v[i] - m; sq += d * d; }
    #pragma unroll
    for (int off = 1; off < 64; off <<= 1) sq += __shfl_xor(sq, off);
    inv = 1.f / (sqrtf(sq * (1.f / (DM - 1))) + EPSLN);

    bf16* zr = z + base;
    #pragma unroll
    for (int i = 0; i < 6; i++) {
        int c = lane + i * 64;
        zr[c] = (bf16)(a0[c] * (v[i] - m) * inv + b0[c]);
    }
}

// ---------------------------------------------------------------------------
// qkv GEMM, LDS-staged, BM=128 BN=64 BK=64 (round-16 proven config).
// grid (64,6,3)=1152 = 4.5 blocks/CU. Weights f32, converted during staging.
// z=0->q, z=1->k, z=2->V^T [b][h][d][s]. Prefetch AFTER barrier B.
// ---------------------------------------------------------------------------
__global__ __launch_bounds__(256) void qkv_kernel(
    const bf16* __restrict__ A,
    const float* __restrict__ wq, const float* __restrict__ wk, const float* __restrict__ wv,
    const float* __restrict__ bq, const float* __restrict__ bk, const float* __restrict__ bv,
    bf16* __restrict__ qkout, bf16* __restrict__ vt)
{
    const int z = blockIdx.z;
    const float* W    = (z == 0) ? wq : (z == 1) ? wk : wv;
    const float* bias = (z == 0) ? bq : (z == 1) ? bk : bv;

    const int t = threadIdx.x;
    const int wave = t >> 6, lane = t & 63;
    const int l15 = lane & 15, quad = lane >> 4;
    const int wr = wave >> 1, wc = wave & 1;
    const int m0 = blockIdx.x * 128;
    const int n0 = blockIdx.y * 64;

    __shared__ __attribute__((aligned(16))) bf16 As[128][72];
    __shared__ __attribute__((aligned(16))) bf16 Bs[64][72];

    const int r0 = t >> 2;            // 0..63
    const int c0 = (t & 3) * 16;      // 0,16,32,48

    const bf16*  aptr0 = A + (size_t)(m0 + r0) * DM + c0;
    const bf16*  aptr1 = A + (size_t)(m0 + 64 + r0) * DM + c0;
    const float* bptr  = W + (size_t)(n0 + r0) * DM + c0;

    bf16x8 ra00 = *(const bf16x8*)(aptr0);
    bf16x8 ra01 = *(const bf16x8*)(aptr0 + 8);
    bf16x8 ra10 = *(const bf16x8*)(aptr1);
    bf16x8 ra11 = *(const bf16x8*)(aptr1 + 8);
    f32x4 wv0 = *(const f32x4*)(bptr);
    f32x4 wv1 = *(const f32x4*)(bptr + 4);
    f32x4 wv2 = *(const f32x4*)(bptr + 8);
    f32x4 wv3 = *(const f32x4*)(bptr + 12);

    f32x4 acc[4][2];
    #pragma unroll
    for (int mi = 0; mi < 4; mi++)
        #pragma unroll
        for (int ni = 0; ni < 2; ni++) acc[mi][ni] = (f32x4){0.f, 0.f, 0.f, 0.f};

    for (int kk = 0; kk < DM; kk += 64) {
        __syncthreads();   // barrier A (drains prev prefetch — hidden)
        *(bf16x8*)&As[r0][c0]          = ra00;
        *(bf16x8*)&As[r0][c0 + 8]      = ra01;
        *(bf16x8*)&As[64 + r0][c0]     = ra10;
        *(bf16x8*)&As[64 + r0][c0 + 8] = ra11;
        {
            bf16x8 b0v, b1v;
            #pragma unroll
            for (int j = 0; j < 4; j++) {
                b0v[j] = (bf16)wv0[j]; b0v[4 + j] = (bf16)wv1[j];
                b1v[j] = (bf16)wv2[j]; b1v[4 + j] = (bf16)wv3[j];
            }
            *(bf16x8*)&Bs[r0][c0]     = b0v;
            *(bf16x8*)&Bs[r0][c0 + 8] = b1v;
        }
        __syncthreads();   // barrier B
        if (kk + 64 < DM) {   // prefetch next K-tile, drains at next barrier A
            ra00 = *(const bf16x8*)(aptr0 + kk + 64);
            ra01 = *(const bf16x8*)(aptr0 + kk + 64 + 8);
            ra10 = *(const bf16x8*)(aptr1 + kk + 64);
            ra11 = *(const bf16x8*)(aptr1 + kk + 64 + 8);
            wv0 = *(const f32x4*)(bptr + kk + 64);
            wv1 = *(const f32x4*)(bptr + kk + 64 + 4);
            wv2 = *(const f32x4*)(bptr + kk + 64 + 8);
            wv3 = *(const f32x4*)(bptr + kk + 64 + 12);
        }

        #pragma unroll
        for (int kc = 0; kc < 64; kc += 32) {
            bf16x8 af[4], bf[2];
            #pragma unroll
            for (int mi = 0; mi < 4; mi++)
                af[mi] = *(const bf16x8*)&As[wr * 64 + mi * 16 + l15][kc + quad * 8];
            #pragma unroll
            for (int ni = 0; ni < 2; ni++)
                bf[ni] = *(const bf16x8*)&Bs[wc * 32 + ni * 16 + l15][kc + quad * 8];
            #pragma unroll
            for (int mi = 0; mi < 4; mi++)
                #pragma unroll
                for (int ni = 0; ni < 2; ni++)
                    acc[mi][ni] = __builtin_amdgcn_mfma_f32_16x16x32_bf16(af[mi], bf[ni], acc[mi][ni], 0, 0, 0);
        }
    }

    if (z < 2) {
        bf16* out = qkout + (size_t)z * ((size_t)NB * SEQ * DM);
        #pragma unroll
        for (int ni = 0; ni < 2; ni++) {
            int col = n0 + wc * 32 + ni * 16 + l15;
            float bb = bias[col];
            #pragma unroll
            for (int mi = 0; mi < 4; mi++) {
                #pragma unroll
                for (int r = 0; r < 4; r++) {
                    int row = m0 + wr * 64 + mi * 16 + quad * 4 + r;
                    out[(size_t)row * DM + col] = (bf16)(acc[mi][ni][r] + bb);
                }
            }
        }
    } else {
        #pragma unroll
        for (int ni = 0; ni < 2; ni++) {
            int col = n0 + wc * 32 + ni * 16 + l15;
            int h = col >> 6, d = col & 63;
            float bb = bias[col];
            #pragma unroll
            for (int mi = 0; mi < 4; mi++) {
                int row0 = m0 + wr * 64 + mi * 16 + quad * 4;
                int b = row0 >> 12, s0 = row0 & (SEQ - 1);
                bf16x4 ov;
                #pragma unroll
                for (int r = 0; r < 4; r++) ov[r] = (bf16)(acc[mi][ni][r] + bb);
                *(bf16x4*)(vt + (((size_t)b * NH + h) * DK + d) * SEQ + s0) = ov;
            }
        }
    }
}

// ---------------------------------------------------------------------------
// proj GEMM, BK=64, fused split reduce (round-15 proven, byte-identical).
// ---------------------------------------------------------------------------
__device__ __forceinline__ bf16x8 combineA(
    const bf16* __restrict__ o0, const bf16* __restrict__ o1,
    const float* __restrict__ lsum, int row, int kcol)
{
    int b = row >> 12, s = row & (SEQ - 1);
    int h = kcol >> 6;
    size_t lidx = ((size_t)b * NH + h) * SEQ + s;
    float inv = 1.f / (lsum[lidx] + lsum[(size_t)(NB * NH * SEQ) + lidx]);
    size_t idx = (size_t)row * DM + kcol;
    bf16x8 a = *(const bf16x8*)(o0 + idx);
    bf16x8 c = *(const bf16x8*)(o1 + idx);
    bf16x8 r;
    #pragma unroll
    for (int j = 0; j < 8; j++) r[j] = (bf16)(((float)a[j] + (float)c[j]) * inv);
    return r;
}

__global__ __launch_bounds__(256) void proj_kernel(
    const bf16* __restrict__ o0, const bf16* __restrict__ o1,
    const float* __restrict__ lsum,
    const float* __restrict__ wo, const float* __restrict__ bo,
    const void* __restrict__ xin, int f32in,
    void* __restrict__ xout, int f32out)
{
    const int t = threadIdx.x;
    const int wave = t >> 6, lane = t & 63;
    const int l15 = lane & 15, quad = lane >> 4;
    const int wr = wave >> 1, wc = wave & 1;
    const int m0 = blockIdx.x * 64;
    const int n0 = blockIdx.y * 64;

    __shared__ __attribute__((aligned(16))) bf16 As[64][72];
    __shared__ __attribute__((aligned(16))) bf16 Bs[64][72];

    const int r0 = t >> 2;
    const int c0 = (t & 3) * 16;
    const int arow = m0 + r0;
    const float* bptr = wo + (size_t)(n0 + r0) * DM + c0;

    bf16x8 ca0 = combineA(o0, o1, lsum, arow, c0);
    bf16x8 ca1 = combineA(o0, o1, lsum, arow, c0 + 8);
    f32x4 wv0 = *(const f32x4*)(bptr);
    f32x4 wv1 = *(const f32x4*)(bptr + 4);
    f32x4 wv2 = *(const f32x4*)(bptr + 8);
    f32x4 wv3 = *(const f32x4*)(bptr + 12);

    f32x4 acc[2][2];
    #pragma unroll
    for (int mi = 0; mi < 2; mi++)
        #pragma unroll
        for (int ni = 0; ni < 2; ni++) acc[mi][ni] = (f32x4){0.f, 0.f, 0.f, 0.f};

    for (int kk = 0; kk < DM; kk += 64) {
        __syncthreads();
        *(bf16x8*)&As[r0][c0]     = ca0;
        *(bf16x8*)&As[r0][c0 + 8] = ca1;
        {
            bf16x8 b0v, b1v;
            #pragma unroll
            for (int j = 0; j < 4; j++) {
                b0v[j] = (bf16)wv0[j]; b0v[4 + j] = (bf16)wv1[j];
                b1v[j] = (bf16)wv2[j]; b1v[4 + j] = (bf16)wv3[j];
            }
            *(bf16x8*)&Bs[r0][c0]     = b0v;
            *(bf16x8*)&Bs[r0][c0 + 8] = b1v;
        }
        __syncthreads();
        if (kk + 64 < DM) {
            ca0 = combineA(o0, o1, lsum, arow, kk + 64 + c0);
            ca1 = combineA(o0, o1, lsum, arow, kk + 64 + c0 + 8);
            wv0 = *(const f32x4*)(bptr + kk + 64);
            wv1 = *(const f32x4*)(bptr + kk + 64 + 4);
            wv2 = *(const f32x4*)(bptr + kk + 64 + 8);
            wv3 = *(const f32x4*)(bptr + kk + 64 + 12);
        }

        #pragma unroll
        for (int kc = 0; kc < 64; kc += 32) {
            bf16x8 af[2], bf[2];
            #pragma unroll
            for (int mi = 0; mi < 2; mi++)
                af[mi] = *(const bf16x8*)&As[wr * 32 + mi * 16 + l15][kc + quad * 8];
            #pragma unroll
            for (int ni = 0; ni < 2; ni++)
                bf[ni] = *(const bf16x8*)&Bs[wc * 32 + ni * 16 + l15][kc + quad * 8];
            #pragma unroll
            for (int mi = 0; mi < 2; mi++)
                #pragma unroll
                for (int ni = 0; ni < 2; ni++)
                    acc[mi][ni] = __builtin_amdgcn_mfma_f32_16x16x32_bf16(af[mi], bf[ni], acc[mi][ni], 0, 0, 0);
        }
    }

    #pragma unroll
    for (int ni = 0; ni < 2; ni++) {
        int col = n0 + wc * 32 + ni * 16 + l15;
        float bb = bo[col];
        #pragma unroll
        for (int mi = 0; mi < 2; mi++) {
            #pragma unroll
            for (int r = 0; r < 4; r++) {
                size_t idx = (size_t)(m0 + wr * 32 + mi * 16 + quad * 4 + r) * DM + col;
                float val = ldT(xin, idx, f32in) + acc[mi][ni][r] + bb;
                if (f32out) ((float*)xout)[idx] = val;
                else        ((bf16*)xout)[idx] = (bf16)val;
            }
        }
    }
}

// ---------------------------------------------------------------------------
// Flash attention — Q-tile 128 (2 q-groups/wave), split-KV x2, KV tile 128
// (round-16 proven, byte-identical).
// ---------------------------------------------------------------------------
__global__ __launch_bounds__(256, 3) void attn_kernel(
    const bf16* __restrict__ q, const bf16* __restrict__ k, const bf16* __restrict__ vt,
    bf16* __restrict__ o0, bf16* __restrict__ o1, float* __restrict__ lsum)
{
    int qt = blockIdx.x, h = blockIdx.y;
    int b = blockIdx.z >> 1, split = blockIdx.z & 1;
    int wave = threadIdx.x >> 6, lane = threadIdx.x & 63;
    int l15 = lane & 15, quad = lane >> 4;
    int q0 = qt * 128;
    const int kvbase = split * (SEQ / 2);
    size_t basebh = (size_t)b * SEQ * DM + (size_t)h * DK;

    __shared__ __attribute__((aligned(16))) bf16 KsP0[128][72];   // Ks; qg0's P aliases
    __shared__ __attribute__((aligned(16))) bf16 Vt[64][136];     // V^T [d][kv]
    __shared__ __attribute__((aligned(16))) bf16 P1[4][16][136];  // qg1's P (dedicated)
    bf16 (*P0)[16][136] = (bf16 (*)[16][136])&KsP0[0][0];

    bf16x8 aq[2][2];
    #pragma unroll
    for (int qg = 0; qg < 2; qg++) {
        const bf16* qp = q + basebh + (size_t)(q0 + qg * 64 + wave * 16 + l15) * DM + quad * 8;
        aq[qg][0] = *(const bf16x8*)(qp);
        aq[qg][1] = *(const bf16x8*)(qp + 32);
    }

    const float c2 = 0.18033688011112042f;   // log2(e)/8
    float lr[2][2] = {{0.f, 0.f}, {0.f, 0.f}};
    f32x4 oacc[2][4];
    #pragma unroll
    for (int qg = 0; qg < 2; qg++)
        #pragma unroll
        for (int mt = 0; mt < 4; mt++) oacc[qg][mt] = (f32x4){0.f, 0.f, 0.f, 0.f};

    const int sd  = threadIdx.x >> 2;
    const int sk0 = (threadIdx.x & 3) * 32;
    const bf16* vtrow0 = vt + (((size_t)b * NH + h) * DK + sd) * SEQ + sk0;
    const int skk = threadIdx.x >> 1;
    const int sdk = (threadIdx.x & 1) * 32;
    const bf16* krow0 = k + basebh + (size_t)skk * DM + sdk;

    bf16x8 vr0 = *(const bf16x8*)(vtrow0 + kvbase);
    bf16x8 vr1 = *(const bf16x8*)(vtrow0 + kvbase + 8);
    bf16x8 vr2 = *(const bf16x8*)(vtrow0 + kvbase + 16);
    bf16x8 vr3 = *(const bf16x8*)(vtrow0 + kvbase + 24);
    bf16x8 kr0 = *(const bf16x8*)(krow0 + (size_t)kvbase * DM);
    bf16x8 kr1 = *(const bf16x8*)(krow0 + (size_t)kvbase * DM + 8);
    bf16x8 kr2 = *(const bf16x8*)(krow0 + (size_t)kvbase * DM + 16);
    bf16x8 kr3 = *(const bf16x8*)(krow0 + (size_t)kvbase * DM + 24);

    for (int it = 0; it < 16; it++) {
        __syncthreads();   // barrier A
        *(bf16x8*)&Vt[sd][sk0]      = vr0;
        *(bf16x8*)&Vt[sd][sk0 + 8]  = vr1;
        *(bf16x8*)&Vt[sd][sk0 + 16] = vr2;
        *(bf16x8*)&Vt[sd][sk0 + 24] = vr3;
        *(bf16x8*)&KsP0[skk][sdk]      = kr0;
        *(bf16x8*)&KsP0[skk][sdk + 8]  = kr1;
        *(bf16x8*)&KsP0[skk][sdk + 16] = kr2;
        *(bf16x8*)&KsP0[skk][sdk + 24] = kr3;
        __syncthreads();   // barrier B

        {   // prefetch next tile: drains at next barrier A
            int kvn = (it + 1 < 16) ? kvbase + (it + 1) * 128 : kvbase;
            const bf16* vp = vtrow0 + kvn;
            vr0 = *(const bf16x8*)(vp);
            vr1 = *(const bf16x8*)(vp + 8);
            vr2 = *(const bf16x8*)(vp + 16);
            vr3 = *(const bf16x8*)(vp + 24);
            const bf16* kp2 = krow0 + (size_t)kvn * DM;
            kr0 = *(const bf16x8*)(kp2);
            kr1 = *(const bf16x8*)(kp2 + 8);
            kr2 = *(const bf16x8*)(kp2 + 16);
            kr3 = *(const bf16x8*)(kp2 + 24);
        }

        bf16x4 pk0[8];
        #pragma unroll
        for (int g = 0; g < 8; g++) {
            bf16x8 kf0 = *(const bf16x8*)&KsP0[g * 16 + l15][quad * 8];
            bf16x8 kf1 = *(const bf16x8*)&KsP0[g * 16 + l15][quad * 8 + 32];
            f32x4 s0 = (f32x4){0.f, 0.f, 0.f, 0.f};
            f32x4 s1 = (f32x4){0.f, 0.f, 0.f, 0.f};
            s0 = __builtin_amdgcn_mfma_f32_16x16x32_bf16(kf0, aq[0][0], s0, 0, 0, 0);
            s1 = __builtin_amdgcn_mfma_f32_16x16x32_bf16(kf0, aq[1][0], s1, 0, 0, 0);
            s0 = __builtin_amdgcn_mfma_f32_16x16x32_bf16(kf1, aq[0][1], s0, 0, 0, 0);
            s1 = __builtin_amdgcn_mfma_f32_16x16x32_bf16(kf1, aq[1][1], s1, 0, 0, 0);
            bf16x4 t1;
            #pragma unroll
            for (int r = 0; r < 4; r++) {
                float p0 = __builtin_amdgcn_exp2f(s0[r] * c2);
                float p1 = __builtin_amdgcn_exp2f(s1[r] * c2);
                lr[0][r & 1] += p0;
                lr[1][r & 1] += p1;
                pk0[g][r] = (bf16)p0;
                t1[r] = (bf16)p1;
            }
            *(bf16x4*)&P1[wave][l15][g * 16 + quad * 4] = t1;
        }

        __syncthreads();   // barrier C: Ks reads done before aliased P0 writes

        #pragma unroll
        for (int g = 0; g < 8; g++)
            *(bf16x4*)&P0[wave][l15][g * 16 + quad * 4] = pk0[g];

        #pragma unroll
        for (int c = 0; c < 4; c++) {
            bf16x8 bp0 = *(const bf16x8*)(&P0[wave][l15][c * 32 + quad * 8]);
            bf16x8 bp1 = *(const bf16x8*)(&P1[wave][l15][c * 32 + quad * 8]);
            #pragma unroll
            for (int mt = 0; mt < 4; mt++) {
                bf16x8 av = *(const bf16x8*)(&Vt[mt * 16 + l15][c * 32 + quad * 8]);
                oacc[0][mt] = __builtin_amdgcn_mfma_f32_16x16x32_bf16(av, bp0, oacc[0][mt], 0, 0, 0);
                oacc[1][mt] = __builtin_amdgcn_mfma_f32_16x16x32_bf16(av, bp1, oacc[1][mt], 0, 0, 0);
            }
        }
    }

    bf16* osel = split ? o1 : o0;
    #pragma unroll
    for (int qg = 0; qg < 2; qg++) {
        float lrun = lr[qg][0] + lr[qg][1];
        lrun += __shfl_xor(lrun, 16);
        lrun += __shfl_xor(lrun, 32);
        int row = q0 + qg * 64 + wave * 16 + l15;
        bf16* op = osel + basebh + (size_t)row * DM + quad * 4;
        #pragma unroll
        for (int mt = 0; mt < 4; mt++) {
            bf16x4 ov;
            #pragma unroll
            for (int r = 0; r < 4; r++) ov[r] = (bf16)oacc[qg][mt][r];
            *(bf16x4*)(op + mt * 16) = ov;
        }
        if (quad == 0)
            lsum[(size_t)split * (NB * NH * SEQ) + ((size_t)b * NH + h) * SEQ + row] = lrun;
    }
}

// ---------------------------------------------------------------------------
extern "C" void kernel_launch(void* const* d_in, const int* in_sizes, int n_in,
                              void* d_out, int out_size, void* d_ws, size_t ws_size,
                              hipStream_t stream) {
    const size_t SZ = (size_t)NB * SEQ * DM;

    const float* x   = (const float*)d_in[0];
    const float* a0  = (const float*)d_in[1];
    const float* b0  = (const float*)d_in[2];
    const float* ra0 = (const float*)d_in[3];
    const float* rb0 = (const float*)d_in[4];
    const float* ra1 = (const float*)d_in[5];
    const float* rb1 = (const float*)d_in[6];
    const float* wq  = (const float*)d_in[7];  const float* bq = (const float*)d_in[8];
    const float* wk  = (const float*)d_in[9];  const float* bk = (const float*)d_in[10];
    const float* wv  = (const float*)d_in[11]; const float* bv = (const float*)d_in[12];
    const float* wo  = (const float*)d_in[13]; const float* bo = (const float*)d_in[14];

    bf16* zob = (bf16*)d_ws;     // z, then attn O~ split-0
    bf16* qb  = zob + SZ;
    bf16* kb  = qb + SZ;
    bf16* vtb = kb + SZ;         // V^T [NB][NH][DK][SEQ]
    bf16* x1  = vtb + SZ;
    bf16* o1b = x1 + SZ;         // attn O~ split-1
    float* lsum = (float*)(o1b + SZ);  // [2][NB][NH][SEQ] f32

    dim3 gLN(NB * SEQ / 4);
    dim3 gG(NB * SEQ / 128, DM / 64, 3);
    dim3 gP(NB * SEQ / 64, DM / 64);
    dim3 gA(SEQ / 128, NH, NB * 2);

    // pass 1
    ln2_kernel<<<gLN, 256, 0, stream>>>(x, 1, ra0, rb0, a0, b0, zob);
    qkv_kernel<<<gG, 256, 0, stream>>>(zob, wq, wk, wv, bq, bk, bv, qb, vtb);
    attn_kernel<<<gA, 256, 0, stream>>>(qb, kb, vtb, zob, o1b, lsum);
    proj_kernel<<<gP, 256, 0, stream>>>(zob, o1b, lsum, wo, bo, x, 1, x1, 0);
    // pass 2
    ln2_kernel<<<gLN, 256, 0, stream>>>(x1, 0, ra1, rb1, a0, b0, zob);
    qkv_kernel<<<gG, 256, 0, stream>>>(zob, wq, wk, wv, bq, bk, bv, qb, vtb);
    attn_kernel<<<gA, 256, 0, stream>>>(qb, kb, vtb, zob, o1b, lsum);
    proj_kernel<<<gP, 256, 0, stream>>>(zob, o1b, lsum, wo, bo, x1, 0, d_out, 1);
}